// Round 8
// baseline (828.463 us; speedup 1.0000x reference)
//
#include <hip/hip_runtime.h>
#include <hip/hip_bf16.h>

#define MDIM 64

typedef __attribute__((ext_vector_type(8))) short short8;
typedef __attribute__((ext_vector_type(4))) float f32x4;

__device__ __forceinline__ unsigned short bf16_of(float x) {
  __hip_bfloat16 b = __float2bfloat16(x);   // RNE
  return *reinterpret_cast<unsigned short*>(&b);
}
__device__ __forceinline__ float f32_of(unsigned short h) {
  return __uint_as_float(((unsigned int)h) << 16);
}
__device__ __forceinline__ void split2(float x, short& h, short& l) {
  unsigned short hh = bf16_of(x);
  h = (short)hh;
  l = (short)bf16_of(x - f32_of(hh));
}

// ---------------- Kernel 1: partial Gram via bf16-split MFMA, dense staging -------
// 4096 blocks x 64 thr (1 wave, wave-private LDS -> no cross-wave coupling).
// Per 32-row chunk: coalesced f32x4 loads (1KB/instr), transpose into stride-33
// LDS (writes 2-way banks = free; frag reads <=2-way = free), fragments read
// contiguous. Symmetry: only the 10 upper tiles (ti<=tj), 30 MFMA vs 48.
template<bool GUARD>
__global__ __launch_bounds__(64, 4) void k_gram(const float* __restrict__ X,
                                                float* __restrict__ partials,
                                                long N, int cpw) {
  __shared__ float xsT[64 * 33];   // transposed chunk: xsT[c*33 + r]
  const int l = threadIdx.x;
  const int col = l & 15;          // 0..15
  const int kg = l >> 4;           // 0..3

  f32x4 acc[10];
#pragma unroll
  for (int i = 0; i < 10; ++i) acc[i] = (f32x4){0.f, 0.f, 0.f, 0.f};

  const long wrow0 = (long)blockIdx.x * cpw * 32;

  for (int c = 0; c < cpw; ++c) {
    long r0 = wrow0 + (long)c * 32;
    if (GUARD && r0 >= N) break;

    // dense coalesced loads: lane covers cols [col*4,col*4+4) of row (i*4+kg)
    f32x4 st[8];
#pragma unroll
    for (int i = 0; i < 8; ++i) {
      long r = r0 + i * 4 + kg;
      if (!GUARD || r < N)
        st[i] = *reinterpret_cast<const f32x4*>(X + r * MDIM + col * 4);
      else
        st[i] = (f32x4){0.f, 0.f, 0.f, 0.f};
    }
    // transpose into LDS (bank = (4m+h+33j+4i)%32 -> exactly 2 lanes/bank = free)
#pragma unroll
    for (int i = 0; i < 8; ++i) {
      int r = i * 4 + kg;
#pragma unroll
      for (int j = 0; j < 4; ++j)
        xsT[(col * 4 + j) * 33 + r] = st[i][j];
    }
    __syncthreads();   // 1-wave block: cheap; orders DS write -> read

    // fragments: frag[b][e] = Xc[k=kg*8+e][b*16+col] -> contiguous in xsT
    short8 fh[4], fl[4];
#pragma unroll
    for (int b = 0; b < 4; ++b) {
      const float* src = &xsT[(b * 16 + col) * 33 + kg * 8];
#pragma unroll
      for (int e = 0; e < 8; ++e) {
        short h, lo;
        split2(src[e], h, lo);
        fh[b][e] = h;
        fl[b][e] = lo;
      }
    }
    __syncthreads();   // xsT fully consumed before next chunk overwrites

#pragma unroll
    for (int ti = 0; ti < 4; ++ti)
#pragma unroll
      for (int tj = ti; tj < 4; ++tj) {
        const int idx = ti * 4 + tj - ((ti * (ti + 1)) >> 1);   // packed upper index
        acc[idx] = __builtin_amdgcn_mfma_f32_16x16x32_bf16(fh[ti], fh[tj], acc[idx], 0, 0, 0);
        acc[idx] = __builtin_amdgcn_mfma_f32_16x16x32_bf16(fh[ti], fl[tj], acc[idx], 0, 0, 0);
        acc[idx] = __builtin_amdgcn_mfma_f32_16x16x32_bf16(fl[ti], fh[tj], acc[idx], 0, 0, 0);
      }
  }

  // C/D layout: n = lane&15 (col), m = kg*4 + q. Tile (ti,tj): D[m][n] = G[ti*16+m][tj*16+n]
  float* p = partials + (long)blockIdx.x * 2560;
#pragma unroll
  for (int tidx = 0; tidx < 10; ++tidx)
#pragma unroll
    for (int q = 0; q < 4; ++q)
      p[tidx * 256 + (kg * 4 + q) * 16 + col] = acc[tidx][q];
}

// ---------------- Kernel 2a/2b: two-stage reduce (packed-symmetric partials) ------
__global__ __launch_bounds__(256) void k_reduce1(const float* __restrict__ partials,
                                                 float* __restrict__ P2, int nblk) {
  int g = blockIdx.x * 256 + threadIdx.x;  // 0..65535
  int e = g & 4095, s = g >> 12;           // element, slice
  int r = e >> 6, c = e & 63;
  int bi = r >> 4, bj = c >> 4, ri = r & 15, ci = c & 15;
  int off;
  if (bi <= bj) off = (bi * 4 + bj - ((bi * (bi + 1)) >> 1)) * 256 + ri * 16 + ci;
  else          off = (bj * 4 + bi - ((bj * (bj + 1)) >> 1)) * 256 + ci * 16 + ri;  // transpose
  int p0 = (nblk * s) >> 4, p1 = (nblk * (s + 1)) >> 4;
  float sum = 0.f;
  for (int p = p0; p < p1; ++p) sum += partials[(long)p * 2560 + off];
  P2[g] = sum;
}

__global__ __launch_bounds__(256) void k_reduce2(const float* __restrict__ P2,
                                                 float* __restrict__ G) {
  int e = blockIdx.x * 256 + threadIdx.x;  // grid 16
  float sum = 0.f;
#pragma unroll
  for (int s = 0; s < 16; ++s) sum += P2[s * 4096 + e];
  G[e] = sum;
}

// ---------------- Kernel 3: Cholesky + triangular inverse, LDS-broadcast ----------
__global__ __launch_bounds__(64) void k_cholinv(const float* __restrict__ G,
                                                unsigned short* __restrict__ Rh,
                                                unsigned short* __restrict__ Rl) {
  __shared__ float Ls[64][65];
  __shared__ float colbuf[64];
  __shared__ float invd[64];
  const int t = threadIdx.x;

  {
    float row[64];
#pragma unroll
    for (int j4 = 0; j4 < 16; ++j4)
      *reinterpret_cast<f32x4*>(&row[j4 * 4]) =
          *reinterpret_cast<const f32x4*>(G + t * MDIM + j4 * 4);

#pragma unroll
    for (int k = 0; k < 64; ++k) {
      colbuf[t] = row[k];
      __syncthreads();
      float inv = 1.f / sqrtf(colbuf[k]);    // uniform
      if (t == 0) invd[k] = inv;
      float lk = row[k] * inv;               // L[t][k]
      row[k] = lk;
      Ls[t][k] = lk;
#pragma unroll
      for (int j = k + 1; j < 64; ++j)
        row[j] = fmaf(-lk, colbuf[j] * inv, row[j]);
      __syncthreads();
    }
  }

  // Lane t: column t of Linv; y[i<t]=0 self-masks the uniform loop.
  float y[64];
#pragma unroll
  for (int i = 0; i < 64; ++i) {
    float s = 0.f;
#pragma unroll
    for (int m = 0; m < i; ++m) s = fmaf(Ls[i][m], y[m], s);  // broadcast reads
    y[i] = (i == t) ? invd[i] : -invd[i] * s;
  }

#pragma unroll
  for (int j = 0; j < 64; ++j) {
    float v = y[j];
    unsigned short h = bf16_of(v);
    Rh[t * MDIM + j] = h;
    Rl[t * MDIM + j] = bf16_of(v - f32_of(h));
  }
}

// ---------------- Kernel 4: Q = X * Rinv via bf16-split MFMA (unchanged) ----------
__global__ __launch_bounds__(256) void k_apply(const float* __restrict__ X,
                                               const unsigned short* __restrict__ Rh,
                                               const unsigned short* __restrict__ Rl,
                                               float* __restrict__ Q, long N) {
  const int t = threadIdx.x;
  const int lane = t & 63;
  const int wave = t >> 6;
  const int col = lane & 15;
  const int kg = lane >> 4;

  short8 bh[4][2], bl[4][2];
#pragma unroll
  for (int jb = 0; jb < 4; ++jb)
#pragma unroll
    for (int kc = 0; kc < 2; ++kc)
#pragma unroll
      for (int e = 0; e < 8; ++e) {
        int k = kc * 32 + kg * 8 + e;
        bh[jb][kc][e] = (short)Rh[k * MDIM + jb * 16 + col];
        bl[jb][kc][e] = (short)Rl[k * MDIM + jb * 16 + col];
      }

  long base = ((long)blockIdx.x * 4 + wave) * 256;
#pragma unroll 1
  for (int i = 0; i < 16; ++i) {
    long r0 = base + i * 16;
    if (r0 >= N) break;
    long rr = r0 + col;
    if (rr > N - 1) rr = N - 1;
    const float* xp = X + rr * MDIM + kg * 8;

    short8 ah[2], al[2];
#pragma unroll
    for (int kc = 0; kc < 2; ++kc) {
      float xv[8];
      *reinterpret_cast<f32x4*>(&xv[0]) = *reinterpret_cast<const f32x4*>(xp + kc * 32);
      *reinterpret_cast<f32x4*>(&xv[4]) = *reinterpret_cast<const f32x4*>(xp + kc * 32 + 4);
#pragma unroll
      for (int e = 0; e < 8; ++e) {
        short h, l;
        split2(xv[e], h, l);
        ah[kc][e] = h;
        al[kc][e] = l;
      }
    }

    f32x4 q[4];
#pragma unroll
    for (int jb = 0; jb < 4; ++jb) q[jb] = (f32x4){0.f, 0.f, 0.f, 0.f};
#pragma unroll
    for (int jb = 0; jb < 4; ++jb)
#pragma unroll
      for (int kc = 0; kc < 2; ++kc) {
        q[jb] = __builtin_amdgcn_mfma_f32_16x16x32_bf16(ah[kc], bh[jb][kc], q[jb], 0, 0, 0);
        q[jb] = __builtin_amdgcn_mfma_f32_16x16x32_bf16(ah[kc], bl[jb][kc], q[jb], 0, 0, 0);
        q[jb] = __builtin_amdgcn_mfma_f32_16x16x32_bf16(al[kc], bh[jb][kc], q[jb], 0, 0, 0);
      }

#pragma unroll
    for (int jb = 0; jb < 4; ++jb)
#pragma unroll
      for (int qq = 0; qq < 4; ++qq) {
        long orow = r0 + kg * 4 + qq;
        if (orow < N) Q[orow * MDIM + jb * 16 + col] = q[jb][qq];
      }
  }
}

extern "C" void kernel_launch(void* const* d_in, const int* in_sizes, int n_in,
                              void* d_out, int out_size, void* d_ws, size_t ws_size,
                              hipStream_t stream) {
  const float* X = (const float*)d_in[0];
  float* Q = (float*)d_out;
  const long N = in_sizes[0] / MDIM;

  float* ws = (float*)d_ws;
  float* G = ws;                                       // 4096 f32
  float* P2 = ws + 4096;                               // 65536 f32
  unsigned short* Rh = (unsigned short*)(ws + 69632);  // 4096 bf16
  unsigned short* Rl = (unsigned short*)(ws + 71680);  // 4096 bf16
  float* partials = ws + 73728;                        // 4096 * 2560 f32 (42 MB)

  const long NBLK = 4096;                              // 1 wave per block
  const long per = NBLK * 32;
  bool exact = (N % per == 0);
  int cpw = (int)((N + per - 1) / per);

  if (exact) k_gram<false><<<NBLK, 64, 0, stream>>>(X, partials, N, cpw);
  else       k_gram<true ><<<NBLK, 64, 0, stream>>>(X, partials, N, cpw);
  k_reduce1<<<256, 256, 0, stream>>>(partials, P2, (int)NBLK);
  k_reduce2<<<16, 256, 0, stream>>>(P2, G);
  k_cholinv<<<1, 64, 0, stream>>>(G, Rh, Rl);
  k_apply<<<(int)((N + 1023) / 1024), 256, 0, stream>>>(X, Rh, Rl, Q, N);
}